// Round 3
// baseline (231.809 us; speedup 1.0000x reference)
//
#include <hip/hip_runtime.h>

typedef unsigned short u16;
typedef unsigned int u32;
typedef unsigned char u8;

#define GG   512
#define NPG  90
#define NTOT (GG*NPG)
#define NED  921600
#define FIN  90
#define HC   64
#define KP   70
#define CAP  64
#define SA   68          // LDS row stride (floats): 68*4=272 ≡ 0 mod 16

// wf (f32 weights in ws) layout, float offsets:
#define WF_W1L 0
#define WF_W1R 5760
#define WF_W2L 11520
#define WF_W2R 15616
#define WF_B1  19712
#define WF_B2  19776
#define WF_FOLD 19840
#define WF_ZC  24320
#define WF_N   24321

__device__ __forceinline__ float bf2f(u16 u) {
    union { u32 i; float f; } v; v.i = ((u32)u) << 16; return v.f;
}
__device__ __forceinline__ u16 f2bf(float f) {
    union { float f; u32 i; } v; v.f = f;
    u32 r = (v.i + 0x7FFFu + ((v.i >> 16) & 1u)) >> 16;
    return (u16)r;
}
__device__ __forceinline__ float ldadp(const void* p, long long i, int isf32) {
    return isf32 ? ((const float*)p)[i] : bf2f(((const u16*)p)[i]);
}

// ---- detect float width (x) and edge int width; write flags[0]=isf32, flags[1]=wide
__global__ void k_detect(const u32* __restrict__ xw, const int* __restrict__ ei,
                         int* __restrict__ flags) {
    if (threadIdx.x == 0) {
        int isf32 = 0;
        for (int i = 0; i < 64; ++i) {
            u32 e = (xw[i] >> 7) & 0xFF;   // exponent field of low-half-as-bf16
            if (e >= 136) isf32 = 1;       // impossible for N(0,1) bf16 data
        }
        flags[0] = isf32;
        int odd = 0;
        for (int i = 1; i < 16; i += 2) odd |= ei[i];
        flags[1] = (odd == 0) ? 1 : 0;     // int64 little-endian high words all 0
    }
}

// ---- per-destination edge lists (local src index; edges stay in-graph)
__global__ void k_build(const int* __restrict__ ei, const int* __restrict__ flags,
                        int* __restrict__ cnt, u8* __restrict__ csr) {
    int e = blockIdx.x * 256 + threadIdx.x;
    if (e >= NED) return;
    int s, d;
    if (flags[1]) { s = ei[2 * e]; d = ei[2 * (NED + e)]; }
    else          { s = ei[e];     d = ei[NED + e];       }
    if ((unsigned)d >= NTOT) return;
    int g = d / NPG;
    int ls = s - g * NPG;
    if ((unsigned)ls >= NPG) return;
    int pos = atomicAdd(&cnt[d], 1);
    if (pos < CAP) csr[d * CAP + pos] = (u8)ls;
}

// ---- convert conv weights to f32 in ws
__global__ void k_convert(const void* W1l, const void* W1r, const void* b1,
                          const void* W2l, const void* W2r, const void* b2,
                          const int* __restrict__ flags, float* __restrict__ wf) {
    int i = blockIdx.x * 256 + threadIdx.x;
    int f32 = flags[0];
    if      (i < 5760)  wf[i] = ldadp(W1l, i, f32);
    else if (i < 11520) wf[i] = ldadp(W1r, i - 5760, f32);
    else if (i < 15616) wf[i] = ldadp(W2l, i - 11520, f32);
    else if (i < 19712) wf[i] = ldadp(W2r, i - 15616, f32);
    else if (i < 19776) wf[i] = ldadp(b1, i - 19712, f32);
    else if (i < 19840) wf[i] = ldadp(b2, i - 19776, f32);
}

// ---- fold MLP: W_fold[m] = sum_j Wl1[m][j]*Wl2[j]; zc = bl1.Wl2 + bl2
__global__ void k_fold(const void* Wl1, const void* bl1, const void* Wl2,
                       const void* bl2, const int* __restrict__ flags,
                       float* __restrict__ wf) {
    int m = blockIdx.x * 256 + threadIdx.x;
    int f32 = flags[0];
    if (m < 4480) {
        float s = 0.f;
        for (int j = 0; j < HC; ++j)
            s += ldadp(Wl1, (long long)m * HC + j, f32) * ldadp(Wl2, j, f32);
        wf[WF_FOLD + m] = s;
    } else if (m == 4480) {
        float s = ldadp(bl2, 0, f32);
        for (int j = 0; j < HC; ++j)
            s += ldadp(bl1, j, f32) * ldadp(Wl2, j, f32);
        wf[WF_ZC] = s;
    }
}

template<bool F32>
__device__ __forceinline__ void do_gemm1(const void* xg, const float* __restrict__ wf,
                                         int n0, int jb,
                                         float accP[3][8], float accQ[3][8]) {
    int rows[3];
    #pragma unroll
    for (int i = 0; i < 3; ++i) rows[i] = (n0 + i < NPG) ? (n0 + i) * FIN : 0;
    for (int k = 0; k < FIN; ++k) {
        float4 l0 = *(const float4*)(wf + WF_W1L + k * HC + jb);
        float4 l1 = *(const float4*)(wf + WF_W1L + k * HC + jb + 4);
        float4 r0 = *(const float4*)(wf + WF_W1R + k * HC + jb);
        float4 r1 = *(const float4*)(wf + WF_W1R + k * HC + jb + 4);
        float wl[8] = {l0.x,l0.y,l0.z,l0.w,l1.x,l1.y,l1.z,l1.w};
        float wr[8] = {r0.x,r0.y,r0.z,r0.w,r1.x,r1.y,r1.z,r1.w};
        #pragma unroll
        for (int i = 0; i < 3; ++i) {
            float xv = F32 ? ((const float*)xg)[rows[i] + k]
                           : bf2f(((const u16*)xg)[rows[i] + k]);
            #pragma unroll
            for (int j = 0; j < 8; ++j) {
                accP[i][j] += xv * wl[j];
                accQ[i][j] += xv * wr[j];
            }
        }
    }
}

// ---- fused per-graph pipeline, all-f32 internal
__global__ __launch_bounds__(256, 2) void k_fused(
    const void* __restrict__ x, const int* __restrict__ cnt,
    const u8* __restrict__ csr, const float* __restrict__ wf,
    const int* __restrict__ flags, void* __restrict__ dout)
{
    __shared__ __align__(16) char smem[49936];
    float* sA    = (float*)smem;                    // [90][68] f32
    float* sB    = (float*)(smem + 24480);          // [90][68] f32
    float* s_rc  = (float*)(smem + 48960);          // [90]
    float* s_key = (float*)(smem + 49320);          // [90]
    float* s_red = (float*)(smem + 49680);          // [4]
    u8*    s_deg = (u8*)(smem + 49696);             // [96]
    u16*   s_ord = (u16*)(smem + 49792);            // [72]

    const int g = blockIdx.x;
    const int t = threadIdx.x;
    const int isf32 = flags[0];
    const int* cnt_g = cnt + g * NPG;
    const u8*  csr_g = csr + g * NPG * CAP;
    const void* xg = isf32 ? (const void*)((const float*)x + g * (NPG * FIN))
                           : (const void*)((const u16*)x + g * (NPG * FIN));

    const int ng = t & 31, jg = t >> 5, jb = jg * 8;
    const int n0 = ng * 3;

    // Phase 0: degrees
    if (t < NPG) {
        int c = cnt_g[t];
        s_deg[t] = (u8)min(c, CAP);
        s_rc[t]  = 1.0f / (float)max(c, 1);
    }

    // Phase 1: P = x@W1l -> sA ; Q = x@W1r + b1 -> regs
    float accP[3][8], accQ[3][8];
    {
        float4 q0 = *(const float4*)(wf + WF_B1 + jb);
        float4 q1 = *(const float4*)(wf + WF_B1 + jb + 4);
        float bias[8] = {q0.x,q0.y,q0.z,q0.w,q1.x,q1.y,q1.z,q1.w};
        #pragma unroll
        for (int i = 0; i < 3; ++i)
            #pragma unroll
            for (int j = 0; j < 8; ++j) { accP[i][j] = 0.f; accQ[i][j] = bias[j]; }
    }
    if (isf32) do_gemm1<true>(xg, wf, n0, jb, accP, accQ);
    else       do_gemm1<false>(xg, wf, n0, jb, accP, accQ);
    #pragma unroll
    for (int i = 0; i < 3; ++i) {
        int n = n0 + i;
        if (n < NPG) {
            *(float4*)(sA + n * SA + jb) =
                make_float4(accP[i][0], accP[i][1], accP[i][2], accP[i][3]);
            *(float4*)(sA + n * SA + jb + 4) =
                make_float4(accP[i][4], accP[i][5], accP[i][6], accP[i][7]);
        }
    }
    __syncthreads();

    // Phase 2: h1 = rc*agg(P) + Q ; write x_train; r1 = relu -> sB
    #pragma unroll
    for (int i = 0; i < 3; ++i) {
        int n = n0 + i;
        if (n < NPG) {
            int deg = s_deg[n];
            float rc = s_rc[n];
            const u8* row = csr_g + n * CAP;
            float acc[8];
            #pragma unroll
            for (int j = 0; j < 8; ++j) acc[j] = 0.f;
            for (int e = 0; e < deg; ++e) {
                int s = row[e];
                const float* ap = sA + s * SA + jb;
                float4 v0 = *(const float4*)ap;
                float4 v1 = *(const float4*)(ap + 4);
                acc[0]+=v0.x; acc[1]+=v0.y; acc[2]+=v0.z; acc[3]+=v0.w;
                acc[4]+=v1.x; acc[5]+=v1.y; acc[6]+=v1.z; acc[7]+=v1.w;
            }
            float h[8];
            #pragma unroll
            for (int j = 0; j < 8; ++j) h[j] = rc * acc[j] + accQ[i][j];
            long long base = 512 + ((long long)(g * NPG + n)) * HC + jb;
            if (isf32) {
                float* o = (float*)dout;
                *(float4*)(o + base)     = make_float4(h[0],h[1],h[2],h[3]);
                *(float4*)(o + base + 4) = make_float4(h[4],h[5],h[6],h[7]);
            } else {
                u16* o = (u16*)dout;
                uint4 pk;
                pk.x = (u32)f2bf(h[0]) | ((u32)f2bf(h[1]) << 16);
                pk.y = (u32)f2bf(h[2]) | ((u32)f2bf(h[3]) << 16);
                pk.z = (u32)f2bf(h[4]) | ((u32)f2bf(h[5]) << 16);
                pk.w = (u32)f2bf(h[6]) | ((u32)f2bf(h[7]) << 16);
                *(uint4*)(o + base) = pk;
            }
            *(float4*)(sB + n * SA + jb) =
                make_float4(fmaxf(h[0],0.f), fmaxf(h[1],0.f), fmaxf(h[2],0.f), fmaxf(h[3],0.f));
            *(float4*)(sB + n * SA + jb + 4) =
                make_float4(fmaxf(h[4],0.f), fmaxf(h[5],0.f), fmaxf(h[6],0.f), fmaxf(h[7],0.f));
        }
    }
    __syncthreads();

    // Phase 3: P2 = r1@W2l -> sA ; Q2 = r1@W2r + b2 -> regs
    {
        float4 q0 = *(const float4*)(wf + WF_B2 + jb);
        float4 q1 = *(const float4*)(wf + WF_B2 + jb + 4);
        float bias[8] = {q0.x,q0.y,q0.z,q0.w,q1.x,q1.y,q1.z,q1.w};
        #pragma unroll
        for (int i = 0; i < 3; ++i)
            #pragma unroll
            for (int j = 0; j < 8; ++j) { accP[i][j] = 0.f; accQ[i][j] = bias[j]; }
    }
    {
        int rows[3];
        #pragma unroll
        for (int i = 0; i < 3; ++i) rows[i] = (n0 + i < NPG) ? (n0 + i) * SA : 0;
        for (int k = 0; k < HC; ++k) {
            float4 l0 = *(const float4*)(wf + WF_W2L + k * HC + jb);
            float4 l1 = *(const float4*)(wf + WF_W2L + k * HC + jb + 4);
            float4 r0 = *(const float4*)(wf + WF_W2R + k * HC + jb);
            float4 r1 = *(const float4*)(wf + WF_W2R + k * HC + jb + 4);
            float wl[8] = {l0.x,l0.y,l0.z,l0.w,l1.x,l1.y,l1.z,l1.w};
            float wr[8] = {r0.x,r0.y,r0.z,r0.w,r1.x,r1.y,r1.z,r1.w};
            #pragma unroll
            for (int i = 0; i < 3; ++i) {
                float rv = sB[rows[i] + k];
                #pragma unroll
                for (int j = 0; j < 8; ++j) {
                    accP[i][j] += rv * wl[j];
                    accQ[i][j] += rv * wr[j];
                }
            }
        }
    }
    __syncthreads();   // all sB reads done; sA may be overwritten
    #pragma unroll
    for (int i = 0; i < 3; ++i) {
        int n = n0 + i;
        if (n < NPG) {
            *(float4*)(sA + n * SA + jb) =
                make_float4(accP[i][0], accP[i][1], accP[i][2], accP[i][3]);
            *(float4*)(sA + n * SA + jb + 4) =
                make_float4(accP[i][4], accP[i][5], accP[i][6], accP[i][7]);
        }
    }
    __syncthreads();

    // Phase 4: h2 = rc*agg(P2) + Q2 -> sB ; key = h2[:,63]
    #pragma unroll
    for (int i = 0; i < 3; ++i) {
        int n = n0 + i;
        if (n < NPG) {
            int deg = s_deg[n];
            float rc = s_rc[n];
            const u8* row = csr_g + n * CAP;
            float acc[8];
            #pragma unroll
            for (int j = 0; j < 8; ++j) acc[j] = 0.f;
            for (int e = 0; e < deg; ++e) {
                int s = row[e];
                const float* ap = sA + s * SA + jb;
                float4 v0 = *(const float4*)ap;
                float4 v1 = *(const float4*)(ap + 4);
                acc[0]+=v0.x; acc[1]+=v0.y; acc[2]+=v0.z; acc[3]+=v0.w;
                acc[4]+=v1.x; acc[5]+=v1.y; acc[6]+=v1.z; acc[7]+=v1.w;
            }
            float h[8];
            #pragma unroll
            for (int j = 0; j < 8; ++j) h[j] = rc * acc[j] + accQ[i][j];
            *(float4*)(sB + n * SA + jb) =
                make_float4(h[0],h[1],h[2],h[3]);
            *(float4*)(sB + n * SA + jb + 4) =
                make_float4(h[4],h[5],h[6],h[7]);
            if (jg == 7) s_key[n] = h[7];
        }
    }
    __syncthreads();

    // Phase 5: stable descending rank (== argsort(-key) stable)
    if (t < NPG) {
        float my = s_key[t];
        int r = 0;
        for (int m2 = 0; m2 < NPG; ++m2) {
            float km = s_key[m2];
            r += (km > my) || (km == my && m2 < t);
        }
        if (r < KP) s_ord[r] = (u16)t;
    }
    __syncthreads();

    // Phase 6: z = sum p*W_fold + zc ; sigmoid
    float zp = 0.f;
    for (int p = t; p < KP * HC; p += 256) {
        int i = p >> 6, c = p & 63;
        int nn = s_ord[i];
        zp += sB[nn * SA + c] * wf[WF_FOLD + p];
    }
    #pragma unroll
    for (int off = 32; off > 0; off >>= 1) zp += __shfl_down(zp, off);
    if ((t & 63) == 0) s_red[t >> 6] = zp;
    __syncthreads();
    if (t == 0) {
        float z = s_red[0] + s_red[1] + s_red[2] + s_red[3] + wf[WF_ZC];
        float sg = 1.0f / (1.0f + expf(-z));
        if (isf32) ((float*)dout)[g] = sg;
        else       ((u16*)dout)[g]   = f2bf(sg);
    }
}

extern "C" void kernel_launch(void* const* d_in, const int* in_sizes, int n_in,
                              void* d_out, int out_size, void* d_ws, size_t ws_size,
                              hipStream_t stream) {
    const void* x   = d_in[0];
    const int*  ei  = (const int*)d_in[1];
    const void* W1l = d_in[3];
    const void* W1r = d_in[4];
    const void* b1  = d_in[5];
    const void* W2l = d_in[6];
    const void* W2r = d_in[7];
    const void* b2  = d_in[8];
    const void* Wl1 = d_in[9];
    const void* bl1 = d_in[10];
    const void* Wl2 = d_in[11];
    const void* bl2 = d_in[12];

    char* ws    = (char*)d_ws;
    int*   flags = (int*)ws;                    // 16 B
    int*   cnt   = (int*)(ws + 64);             // 184,320 B
    u8*    csr   = (u8*)(ws + 184384);          // 2,949,120 B
    float* wf    = (float*)(ws + 3133504);      // 97,284 B   (total ~3.23 MB)

    hipMemsetAsync(cnt, 0, NTOT * sizeof(int), stream);
    k_detect<<<1, 64, 0, stream>>>((const u32*)x, ei, flags);
    k_convert<<<78, 256, 0, stream>>>(W1l, W1r, b1, W2l, W2r, b2, flags, wf);
    k_fold<<<18, 256, 0, stream>>>(Wl1, bl1, Wl2, bl2, flags, wf);
    k_build<<<(NED + 255) / 256, 256, 0, stream>>>(ei, flags, cnt, csr);
    k_fused<<<GG, 256, 0, stream>>>(x, cnt, csr, wf, flags, d_out);
}

// Round 4
// 230.932 us; speedup vs baseline: 1.0038x; 1.0038x over previous
//
#include <hip/hip_runtime.h>

typedef unsigned short u16;
typedef unsigned int u32;
typedef unsigned char u8;
typedef unsigned long long u64;

#define GG   512
#define NPG  90
#define NTOT (GG*NPG)
#define NED  921600
#define FIN  90
#define HC   64
#define KP   70
#define CAP  64
#define SA   68          // f32 LDS row stride; 272B = 16B-aligned, bank-quad = (17n+q)&7

// wf (f32 weights in ws) layout, float offsets:
#define WF_W1L 0
#define WF_W1R 5760
#define WF_W2L 11520
#define WF_W2R 15616
#define WF_B1  19712
#define WF_B2  19776
#define WF_FOLD 19840
#define WF_ZC  24320
#define WF_FLAG 24321

__device__ __forceinline__ float bf2f(u16 u) {
    union { u32 i; float f; } v; v.i = ((u32)u) << 16; return v.f;
}
__device__ __forceinline__ float bflo(u32 u) {
    union { u32 i; float f; } v; v.i = u << 16; return v.f;
}
__device__ __forceinline__ float bfhi(u32 u) {
    union { u32 i; float f; } v; v.i = u & 0xFFFF0000u; return v.f;
}
__device__ __forceinline__ u16 f2bf(float f) {
    union { float f; u32 i; } v; v.f = f;
    u32 r = (v.i + 0x7FFFu + ((v.i >> 16) & 1u)) >> 16;
    return (u16)r;
}
__device__ __forceinline__ float ldadp(const void* p, long long i, int isf32) {
    return isf32 ? ((const float*)p)[i] : bf2f(((const u16*)p)[i]);
}

// ---- merged: dtype-detect + weight convert + MLP fold. Publishes flag via wf.
__global__ void k_prep(const u32* __restrict__ xw,
                       const void* W1l, const void* W1r, const void* b1,
                       const void* W2l, const void* W2r, const void* b2,
                       const void* Wl1, const void* bl1, const void* Wl2,
                       const void* bl2, float* __restrict__ wf) {
    __shared__ int sf;
    int t = threadIdx.x;
    if (t < 64) {
        u32 e = (xw[t] >> 7) & 0xFF;       // exponent of low-half-as-bf16
        u64 b = __ballot(e >= 136);        // impossible for N(0,1)-scale bf16 data
        if (t == 0) sf = (b != 0ull) ? 1 : 0;
    }
    __syncthreads();
    const int f32 = sf;
    const int blk = blockIdx.x;
    if (blk < 78) {
        int i = blk * 256 + t;
        if      (i < 5760)  wf[i] = ldadp(W1l, i, f32);
        else if (i < 11520) wf[i] = ldadp(W1r, i - 5760, f32);
        else if (i < 15616) wf[i] = ldadp(W2l, i - 11520, f32);
        else if (i < 19712) wf[i] = ldadp(W2r, i - 15616, f32);
        else if (i < 19776) wf[i] = ldadp(b1, i - 19712, f32);
        else if (i < 19840) wf[i] = ldadp(b2, i - 19776, f32);
        if (blk == 0 && t == 0) wf[WF_FLAG] = f32 ? 1.0f : 0.0f;
    } else {
        int m = (blk - 78) * 256 + t;
        if (m < 4480) {
            float s = 0.f;
            for (int j = 0; j < HC; ++j)
                s += ldadp(Wl1, (long long)m * HC + j, f32) * ldadp(Wl2, j, f32);
            wf[WF_FOLD + m] = s;
        } else if (m == 4480) {
            float s = ldadp(bl2, 0, f32);
            for (int j = 0; j < HC; ++j)
                s += ldadp(bl1, j, f32) * ldadp(Wl2, j, f32);
            wf[WF_ZC] = s;
        }
    }
}

// ---- per-destination edge lists (local src index; edges stay in-graph)
__global__ void k_build(const int* __restrict__ ei, int* __restrict__ cnt,
                        u8* __restrict__ csr) {
    int t = threadIdx.x;
    int lane = t & 63;
    u32 v = 0;
    if (lane < 16) v = (u32)ei[lane];
    u64 b = __ballot((lane & 1) && (v != 0));  // int64 hi-words all zero -> wide
    bool wide = (b == 0ull);
    int e = blockIdx.x * 256 + t;
    if (e >= NED) return;
    int s, d;
    if (wide) { s = ei[2 * e]; d = ei[2 * (NED + e)]; }
    else      { s = ei[e];     d = ei[NED + e];       }
    if ((unsigned)d >= NTOT) return;
    int g = d / NPG;
    int ls = s - g * NPG;
    if ((unsigned)ls >= NPG) return;
    int pos = atomicAdd(&cnt[d], 1);
    if (pos < CAP) csr[d * CAP + pos] = (u8)ls;
}

// ---- fused per-graph pipeline, all-f32 internal, register-resident aggregation
__global__ __launch_bounds__(256, 2) void k_fused(
    const void* __restrict__ x, const int* __restrict__ cnt,
    const u8* __restrict__ csr, const float* __restrict__ wf,
    void* __restrict__ dout)
{
    __shared__ __align__(16) char smem[55808];
    float* A1    = (float*)smem;                 // [90][68] P -> r1 -> P2 -> h2
    float* A2    = (float*)(smem + 24480);       // [90][68] xstage -> Q -> Q2
    u8*    s_adj = (u8*)(smem + 48960);          // [90][64]
    float* s_rc  = (float*)(smem + 54720);       // [90]
    float* s_key = (float*)(smem + 55080);       // [90]
    float* s_red = (float*)(smem + 55440);       // [4]
    u8*    s_deg = (u8*)(smem + 55456);          // [96]
    u16*   s_ord = (u16*)(smem + 55552);         // [72]

    const int g = blockIdx.x;
    const int t = threadIdx.x;
    const bool isf32 = (wf[WF_FLAG] > 0.5f);

    const u8* csr_g = csr + g * NPG * CAP;
    const u16*  xg16 = (const u16*)x + (size_t)g * NPG * FIN;
    const float* xg32 = (const float*)x + (size_t)g * NPG * FIN;

    // ---- stage: adjacency + degrees + x(bf16 raw) ----
    for (int i = t; i < 360; i += 256)
        ((uint4*)s_adj)[i] = ((const uint4*)csr_g)[i];
    if (t < NPG) {
        int c = cnt[g * NPG + t];
        s_deg[t] = (u8)min(c, CAP);
        s_rc[t]  = 1.0f / (float)max(c, 1);
    }
    if (!isf32) {
        u32* sxw = (u32*)A2;                       // [90][46] u32 (stride 92 u16)
        const u32* src = (const u32*)xg16;
        for (int p = t; p < 4050; p += 256) {
            int row = p / 45, c = p - row * 45;
            sxw[row * 46 + c] = src[p];
        }
    }
    __syncthreads();  // B0

    const int ng = t & 31, jg = t >> 5, jb = jg * 8;
    const int n0 = ng * 3;
    int rows[3];
    #pragma unroll
    for (int i = 0; i < 3; ++i) rows[i] = (n0 + i < NPG) ? n0 + i : 0;

    // ---- GEMM1: P = x@W1l, Q = x@W1r + b1 (regs) ----
    float accP[3][8], accQ[3][8];
    {
        float4 q0 = *(const float4*)(wf + WF_B1 + jb);
        float4 q1 = *(const float4*)(wf + WF_B1 + jb + 4);
        float bias[8] = {q0.x,q0.y,q0.z,q0.w,q1.x,q1.y,q1.z,q1.w};
        #pragma unroll
        for (int i = 0; i < 3; ++i)
            #pragma unroll
            for (int j = 0; j < 8; ++j) { accP[i][j] = 0.f; accQ[i][j] = bias[j]; }
    }
    {
        const u32* sxw = (const u32*)A2;
        for (int kk = 0; kk < 45; ++kk) {
            const int k0 = 2 * kk;
            const float* wl = wf + WF_W1L + k0 * HC + jb;
            const float* wr = wf + WF_W1R + k0 * HC + jb;
            float4 l00 = *(const float4*)(wl);
            float4 l01 = *(const float4*)(wl + 4);
            float4 l10 = *(const float4*)(wl + HC);
            float4 l11 = *(const float4*)(wl + HC + 4);
            float4 r00 = *(const float4*)(wr);
            float4 r01 = *(const float4*)(wr + 4);
            float4 r10 = *(const float4*)(wr + HC);
            float4 r11 = *(const float4*)(wr + HC + 4);
            float wl0[8] = {l00.x,l00.y,l00.z,l00.w,l01.x,l01.y,l01.z,l01.w};
            float wl1[8] = {l10.x,l10.y,l10.z,l10.w,l11.x,l11.y,l11.z,l11.w};
            float wr0[8] = {r00.x,r00.y,r00.z,r00.w,r01.x,r01.y,r01.z,r01.w};
            float wr1[8] = {r10.x,r10.y,r10.z,r10.w,r11.x,r11.y,r11.z,r11.w};
            float x0[3], x1[3];
            if (!isf32) {
                #pragma unroll
                for (int i = 0; i < 3; ++i) {
                    u32 xv = sxw[rows[i] * 46 + kk];
                    x0[i] = bflo(xv); x1[i] = bfhi(xv);
                }
            } else {
                #pragma unroll
                for (int i = 0; i < 3; ++i) {
                    x0[i] = xg32[rows[i] * FIN + k0];
                    x1[i] = xg32[rows[i] * FIN + k0 + 1];
                }
            }
            #pragma unroll
            for (int i = 0; i < 3; ++i)
                #pragma unroll
                for (int j = 0; j < 8; ++j) {
                    accP[i][j] += x0[i] * wl0[j] + x1[i] * wl1[j];
                    accQ[i][j] += x0[i] * wr0[j] + x1[i] * wr1[j];
                }
        }
    }
    __syncthreads();  // B1: x-stage reads complete, A2 reusable
    #pragma unroll
    for (int i = 0; i < 3; ++i) {
        int n = n0 + i;
        if (n < NPG) {
            *(float4*)(A1 + n * SA + jb) =
                make_float4(accP[i][0], accP[i][1], accP[i][2], accP[i][3]);
            *(float4*)(A1 + n * SA + jb + 4) =
                make_float4(accP[i][4], accP[i][5], accP[i][6], accP[i][7]);
            *(float4*)(A2 + n * SA + jb) =
                make_float4(accQ[i][0], accQ[i][1], accQ[i][2], accQ[i][3]);
            *(float4*)(A2 + n * SA + jb + 4) =
                make_float4(accQ[i][4], accQ[i][5], accQ[i][6], accQ[i][7]);
        }
    }
    __syncthreads();  // B2

    // ---- Agg1: h1 = rc*sum(P[nbr]) + Q ; x_train out; r1 in regs ----
    const int gl = t & 15, gid = t >> 4;
    float r1v[6][4];
    #pragma unroll
    for (int p = 0; p < 6; ++p) {
        int n = p * 16 + gid;
        if (n < NPG) {
            int q4 = ((gl + n) & 15) * 4;          // rotated quad: bank-balanced
            int deg = s_deg[n];
            float4 acc = make_float4(0.f, 0.f, 0.f, 0.f);
            const u8* arow = s_adj + n * CAP;
            for (int e = 0; e < deg; ++e) {
                int s = arow[e];
                float4 v = *(const float4*)(A1 + s * SA + q4);
                acc.x += v.x; acc.y += v.y; acc.z += v.z; acc.w += v.w;
            }
            float rc = s_rc[n];
            float4 qv = *(const float4*)(A2 + n * SA + q4);
            float h0 = fmaf(rc, acc.x, qv.x);
            float h1 = fmaf(rc, acc.y, qv.y);
            float h2 = fmaf(rc, acc.z, qv.z);
            float h3 = fmaf(rc, acc.w, qv.w);
            size_t base = 512 + (size_t)(g * NPG + n) * HC + q4;
            if (isf32) {
                *(float4*)((float*)dout + base) = make_float4(h0, h1, h2, h3);
            } else {
                uint2 pk;
                pk.x = (u32)f2bf(h0) | ((u32)f2bf(h1) << 16);
                pk.y = (u32)f2bf(h2) | ((u32)f2bf(h3) << 16);
                *(uint2*)((u16*)dout + base) = pk;
            }
            r1v[p][0] = fmaxf(h0, 0.f); r1v[p][1] = fmaxf(h1, 0.f);
            r1v[p][2] = fmaxf(h2, 0.f); r1v[p][3] = fmaxf(h3, 0.f);
        }
    }
    __syncthreads();  // B3: all P/Q reads done
    #pragma unroll
    for (int p = 0; p < 6; ++p) {
        int n = p * 16 + gid;
        if (n < NPG) {
            int q4 = ((gl + n) & 15) * 4;
            *(float4*)(A1 + n * SA + q4) =
                make_float4(r1v[p][0], r1v[p][1], r1v[p][2], r1v[p][3]);
        }
    }
    __syncthreads();  // B4

    // ---- GEMM2: P2 = r1@W2l, Q2 = r1@W2r + b2 (regs) ----
    {
        float4 q0 = *(const float4*)(wf + WF_B2 + jb);
        float4 q1 = *(const float4*)(wf + WF_B2 + jb + 4);
        float bias[8] = {q0.x,q0.y,q0.z,q0.w,q1.x,q1.y,q1.z,q1.w};
        #pragma unroll
        for (int i = 0; i < 3; ++i)
            #pragma unroll
            for (int j = 0; j < 8; ++j) { accP[i][j] = 0.f; accQ[i][j] = bias[j]; }
    }
    {
        int rws[3];
        #pragma unroll
        for (int i = 0; i < 3; ++i) rws[i] = rows[i] * SA;
        for (int k = 0; k < HC; ++k) {
            const float* wl = wf + WF_W2L + k * HC + jb;
            const float* wr = wf + WF_W2R + k * HC + jb;
            float4 l0 = *(const float4*)(wl);
            float4 l1 = *(const float4*)(wl + 4);
            float4 r0 = *(const float4*)(wr);
            float4 r1q = *(const float4*)(wr + 4);
            float wlv[8] = {l0.x,l0.y,l0.z,l0.w,l1.x,l1.y,l1.z,l1.w};
            float wrv[8] = {r0.x,r0.y,r0.z,r0.w,r1q.x,r1q.y,r1q.z,r1q.w};
            #pragma unroll
            for (int i = 0; i < 3; ++i) {
                float rv = A1[rws[i] + k];
                #pragma unroll
                for (int j = 0; j < 8; ++j) {
                    accP[i][j] += rv * wlv[j];
                    accQ[i][j] += rv * wrv[j];
                }
            }
        }
    }
    __syncthreads();  // B5: all r1 reads done
    #pragma unroll
    for (int i = 0; i < 3; ++i) {
        int n = n0 + i;
        if (n < NPG) {
            *(float4*)(A1 + n * SA + jb) =
                make_float4(accP[i][0], accP[i][1], accP[i][2], accP[i][3]);
            *(float4*)(A1 + n * SA + jb + 4) =
                make_float4(accP[i][4], accP[i][5], accP[i][6], accP[i][7]);
            *(float4*)(A2 + n * SA + jb) =
                make_float4(accQ[i][0], accQ[i][1], accQ[i][2], accQ[i][3]);
            *(float4*)(A2 + n * SA + jb + 4) =
                make_float4(accQ[i][4], accQ[i][5], accQ[i][6], accQ[i][7]);
        }
    }
    __syncthreads();  // B6

    // ---- Agg2: h2 = rc*sum(P2[nbr]) + Q2 ; key = h2[:,63] ----
    float h2v[6][4];
    #pragma unroll
    for (int p = 0; p < 6; ++p) {
        int n = p * 16 + gid;
        if (n < NPG) {
            int q4 = ((gl + n) & 15) * 4;
            int deg = s_deg[n];
            float4 acc = make_float4(0.f, 0.f, 0.f, 0.f);
            const u8* arow = s_adj + n * CAP;
            for (int e = 0; e < deg; ++e) {
                int s = arow[e];
                float4 v = *(const float4*)(A1 + s * SA + q4);
                acc.x += v.x; acc.y += v.y; acc.z += v.z; acc.w += v.w;
            }
            float rc = s_rc[n];
            float4 qv = *(const float4*)(A2 + n * SA + q4);
            h2v[p][0] = fmaf(rc, acc.x, qv.x);
            h2v[p][1] = fmaf(rc, acc.y, qv.y);
            h2v[p][2] = fmaf(rc, acc.z, qv.z);
            h2v[p][3] = fmaf(rc, acc.w, qv.w);
            if (q4 == 60) s_key[n] = h2v[p][3];
        }
    }
    __syncthreads();  // B7: all P2/Q2 reads done; s_key complete
    #pragma unroll
    for (int p = 0; p < 6; ++p) {
        int n = p * 16 + gid;
        if (n < NPG) {
            int q4 = ((gl + n) & 15) * 4;
            *(float4*)(A1 + n * SA + q4) =
                make_float4(h2v[p][0], h2v[p][1], h2v[p][2], h2v[p][3]);
        }
    }
    // stable descending rank (== stable argsort(-key))
    if (t < NPG) {
        float my = s_key[t];
        int r = 0;
        for (int m2 = 0; m2 < NPG; ++m2) {
            float km = s_key[m2];
            r += (km > my) || (km == my && m2 < t);
        }
        if (r < KP) s_ord[r] = (u16)t;
    }
    __syncthreads();  // B8

    // ---- folded MLP: z = sum p*W_fold + zc ; sigmoid ----
    float zp = 0.f;
    for (int p2 = t; p2 < KP * HC; p2 += 256) {
        int i = p2 >> 6, c = p2 & 63;
        int nn = s_ord[i];
        zp += A1[nn * SA + c] * wf[WF_FOLD + p2];
    }
    #pragma unroll
    for (int off = 32; off > 0; off >>= 1) zp += __shfl_down(zp, off);
    if ((t & 63) == 0) s_red[t >> 6] = zp;
    __syncthreads();  // B9
    if (t == 0) {
        float z = s_red[0] + s_red[1] + s_red[2] + s_red[3] + wf[WF_ZC];
        float sg = 1.0f / (1.0f + expf(-z));
        if (isf32) ((float*)dout)[g] = sg;
        else       ((u16*)dout)[g]   = f2bf(sg);
    }
}

extern "C" void kernel_launch(void* const* d_in, const int* in_sizes, int n_in,
                              void* d_out, int out_size, void* d_ws, size_t ws_size,
                              hipStream_t stream) {
    const void* x   = d_in[0];
    const int*  ei  = (const int*)d_in[1];
    const void* W1l = d_in[3];
    const void* W1r = d_in[4];
    const void* b1  = d_in[5];
    const void* W2l = d_in[6];
    const void* W2r = d_in[7];
    const void* b2  = d_in[8];
    const void* Wl1 = d_in[9];
    const void* bl1 = d_in[10];
    const void* Wl2 = d_in[11];
    const void* bl2 = d_in[12];

    char* ws    = (char*)d_ws;
    int*   cnt  = (int*)(ws + 64);              // 184,320 B
    u8*    csr  = (u8*)(ws + 184384);           // 2,949,120 B
    float* wf   = (float*)(ws + 3133504);       // 97,288 B   (total ~3.23 MB)

    hipMemsetAsync(cnt, 0, NTOT * sizeof(int), stream);
    k_prep<<<96, 256, 0, stream>>>((const u32*)x, W1l, W1r, b1, W2l, W2r, b2,
                                   Wl1, bl1, Wl2, bl2, wf);
    k_build<<<(NED + 255) / 256, 256, 0, stream>>>(ei, cnt, csr);
    k_fused<<<GG, 256, 0, stream>>>(x, cnt, csr, wf, d_out);
}